// Round 19
// baseline (292.658 us; speedup 1.0000x reference)
//
#include <hip/hip_runtime.h>
#include <hip/hip_bf16.h>

#define N_DIM 8192
#define E_DIM 2048
#define NKT 64           // K tiles of BK=32

typedef __bf16 bf16x8 __attribute__((ext_vector_type(8)));
typedef float  f32x4  __attribute__((ext_vector_type(4)));
typedef short  short8 __attribute__((ext_vector_type(8)));

#define GLD(gp, lp) __builtin_amdgcn_global_load_lds( \
    (const __attribute__((address_space(1))) void*)(gp), \
    (__attribute__((address_space(3))) void*)(lp), 16, 0, 0)
#define MFMA16(a, b, c) __builtin_amdgcn_mfma_f32_16x16x32_bf16(a, b, c, 0, 0, 0)
#define SBAR() __builtin_amdgcn_sched_barrier(0)

// ---------------- conversion: A fp32 [N,E] -> bf16 [N,E] ----------------
__global__ __launch_bounds__(256) void cvtA(const float* __restrict__ A,
                                            __hip_bfloat16* __restrict__ Abf) {
    size_t i = ((size_t)blockIdx.x * 256 + threadIdx.x) * 8;
    float4 f0 = *reinterpret_cast<const float4*>(A + i);
    float4 f1 = *reinterpret_cast<const float4*>(A + i + 4);
    union { short8 s8; __hip_bfloat16 h[8]; } u;
    u.h[0] = __float2bfloat16(f0.x);
    u.h[1] = __float2bfloat16(f0.y);
    u.h[2] = __float2bfloat16(f0.z);
    u.h[3] = __float2bfloat16(f0.w);
    u.h[4] = __float2bfloat16(f1.x);
    u.h[5] = __float2bfloat16(f1.y);
    u.h[6] = __float2bfloat16(f1.z);
    u.h[7] = __float2bfloat16(f1.w);
    *reinterpret_cast<short8*>(&Abf[i]) = u.s8;
}

// ------- scale+transpose: Bt[n,e] = W[e] * B[e,n], fp32 -> bf16 ---------
__global__ __launch_bounds__(256) void cvtB(const float* __restrict__ B,
                                            const float* __restrict__ W,
                                            __hip_bfloat16* __restrict__ Bt) {
    __shared__ float tile[32][33];
    const int tx = threadIdx.x & 31;
    const int ty = threadIdx.x >> 5;
    const int n0 = blockIdx.x * 32;
    const int e0 = blockIdx.y * 32;
#pragma unroll
    for (int r = 0; r < 4; ++r) {
        int e = e0 + ty + r * 8;
        tile[ty + r * 8][tx] = B[(size_t)e * N_DIM + n0 + tx] * W[e];
    }
    __syncthreads();
#pragma unroll
    for (int r = 0; r < 4; ++r) {
        int n = n0 + ty + r * 8;
        Bt[(size_t)n * E_DIM + e0 + tx] = __float2bfloat16(tile[tx][ty + r * 8]);
    }
}

// ---------------- GEMM: C[N,N] = Abf[N,E] * Btbf[N,E]^T ----------------
// Barrier-minimal K-loop: ONE barrier per K-tile (BK=32, 4-slot ring),
// zero intra-tile barriers, counted lgkm/vmcnt waits, register read-ahead
// one tile deep. Waves drift within a tile so reads overlap MFMAs across
// waves. R2's verified zero-conflict XOR staging/read addressing; XCD-
// column mapping; R18's verified LDS-band epilogue.
//
// Per-wave lgkm ledger (DS completes in order; GLD uses vmcnt only):
//   entry: [aM0:4, bN0:2, bN1:2] outstanding (read during prev tile)
//   ph0: issue aM1(4) -> 12; lgkm(6) drains aM0,bN0; MFMA(M0,N0)
//   ph1: lgkm(4) drains bN1; MFMA(M0,N1); vmcnt(VM); issue aM0'(4)
//   ph2: lgkm(4) drains aM1 (leaves aM0'); MFMA(M1,N0)
//   ph3: MFMA(M1,N1); issue bN0'(2),bN1'(2)  -> exit = entry invariant
// vmcnt(4) at tile kt drains this wave's slot kt+1 AND kt+2 GLDs, so at
// barrier kt+1 slot kt+2 is globally complete -> read-ahead is race-free.

template<int VM, bool STG, bool NEXT>
__device__ __forceinline__ void ktile(char* ldsA, char* ldsB, int kt,
    int tid, int wave, int wm, int wn, int fr, int sp,
    const char*& aP0, const char*& aP1, const char*& bP0, const char*& bP1,
    bf16x8 (&aM0)[4], bf16x8 (&aM1)[4], bf16x8 (&bN0)[2], bf16x8 (&bN1)[2],
    f32x4 (&acc)[8][4])
{
    const char* Ac = ldsA + (kt & 3) * 16384;
    const char* Bc = ldsB + (kt & 3) * 16384;
    const char* An = ldsA + ((kt + 1) & 3) * 16384;
    const char* Bn = ldsB + ((kt + 1) & 3) * 16384;

    __builtin_amdgcn_s_barrier();   // publish slot kt+1 (global); WAR-release slot kt+3
    SBAR();
    if (STG) {                      // stage tile kt+3 into ring slot (kt+3)&3
        char* dA = ldsA + ((kt + 3) & 3) * 16384 + wave * 1024;
        char* dB = ldsB + ((kt + 3) & 3) * 16384 + wave * 1024;
        GLD(aP0, dA); GLD(aP1, dA + 8192);
        GLD(bP0, dB); GLD(bP1, dB + 8192);
        aP0 += 64; aP1 += 64; bP0 += 64; bP1 += 64;
    }
    SBAR();

    // ---- ph0: issue aM1; wait aM0,bN0; MFMA(M0,N0) ----
#pragma unroll
    for (int f = 0; f < 4; ++f)
        aM1[f] = *reinterpret_cast<const bf16x8*>(Ac + (wm * 128 + 64 + f * 16 + fr) * 64 + sp * 16);
    SBAR();
    asm volatile("s_waitcnt lgkmcnt(6)" ::: "memory");
    SBAR();
    __builtin_amdgcn_s_setprio(1);
#pragma unroll
    for (int f = 0; f < 4; ++f)
#pragma unroll
        for (int n = 0; n < 2; ++n)
            acc[f][n] = MFMA16(aM0[f], bN0[n], acc[f][n]);
    __builtin_amdgcn_s_setprio(0);
    SBAR();

    // ---- ph1: wait bN1; MFMA(M0,N1); then vmcnt + read-ahead aM0' ----
    asm volatile("s_waitcnt lgkmcnt(4)" ::: "memory");
    SBAR();
    __builtin_amdgcn_s_setprio(1);
#pragma unroll
    for (int f = 0; f < 4; ++f)
#pragma unroll
        for (int n = 0; n < 2; ++n)
            acc[f][2 + n] = MFMA16(aM0[f], bN1[n], acc[f][2 + n]);
    __builtin_amdgcn_s_setprio(0);
    SBAR();
    if (NEXT) {
        asm volatile("s_waitcnt vmcnt(%0)" :: "n"(VM) : "memory");
        SBAR();
#pragma unroll
        for (int f = 0; f < 4; ++f)
            aM0[f] = *reinterpret_cast<const bf16x8*>(An + (wm * 128 + f * 16 + fr) * 64 + sp * 16);
        SBAR();
    }

    // ---- ph2: wait aM1; MFMA(M1,N0) ----
    asm volatile("s_waitcnt lgkmcnt(%0)" :: "n"(NEXT ? 4 : 0) : "memory");
    SBAR();
    __builtin_amdgcn_s_setprio(1);
#pragma unroll
    for (int f = 0; f < 4; ++f)
#pragma unroll
        for (int n = 0; n < 2; ++n)
            acc[4 + f][n] = MFMA16(aM1[f], bN0[n], acc[4 + f][n]);
    __builtin_amdgcn_s_setprio(0);
    SBAR();

    // ---- ph3: MFMA(M1,N1); then read-ahead bN0',bN1' ----
    __builtin_amdgcn_s_setprio(1);
#pragma unroll
    for (int f = 0; f < 4; ++f)
#pragma unroll
        for (int n = 0; n < 2; ++n)
            acc[4 + f][2 + n] = MFMA16(aM1[f], bN1[n], acc[4 + f][2 + n]);
    __builtin_amdgcn_s_setprio(0);
    SBAR();
    if (NEXT) {
#pragma unroll
        for (int n = 0; n < 2; ++n)
            bN0[n] = *reinterpret_cast<const bf16x8*>(Bn + (wn * 64 + n * 16 + fr) * 64 + sp * 16);
#pragma unroll
        for (int n = 0; n < 2; ++n)
            bN1[n] = *reinterpret_cast<const bf16x8*>(Bn + (wn * 64 + 32 + n * 16 + fr) * 64 + sp * 16);
        SBAR();
    }
}

__global__ __launch_bounds__(512, 2) void gemm_bt(const __hip_bfloat16* __restrict__ A,
                                                  const __hip_bfloat16* __restrict__ B,
                                                  float* __restrict__ C) {
    __shared__ __align__(16) char lds[131072];
    char* ldsA = (char*)lds;            // 4 slots x 16 KiB (256 rows x 64 B)
    char* ldsB = (char*)lds + 65536;    // 4 slots x 16 KiB

    const int tid  = threadIdx.x;
    const int lane = tid & 63;
    const int wave = tid >> 6;
    const int wm = wave >> 2;          // 0..1
    const int wn = wave & 3;           // 0..3
    const int fr = lane & 15;
    const int sp = (lane >> 4) ^ ((fr >> 1) & 3);   // phys k-slot (0 conflicts, verified)

    // XCD-column mapping (FETCH-verified): XCD owns 4 tile-columns.
    const int bid = blockIdx.x;
    const int xcd = bid & 7;
    const int sub = (bid >> 3) & 3;
    const int tm  = bid >> 5;          // 0..31
    const int tn  = xcd * 4 + sub;     // 0..31

    // staging source pointers (pre-swizzled k-slot, rule 21; R2-verified)
    const char *aP0, *aP1, *bP0, *bP1;
    {
        int g = tid, r = g >> 2, sl = (g & 3) ^ ((r >> 1) & 3);
        aP0 = (const char*)A + ((size_t)(tm * 256 + r) * E_DIM + sl * 8) * 2;
        bP0 = (const char*)B + ((size_t)(tn * 256 + r) * E_DIM + sl * 8) * 2;
        g = tid + 512; r = g >> 2; sl = (g & 3) ^ ((r >> 1) & 3);
        aP1 = (const char*)A + ((size_t)(tm * 256 + r) * E_DIM + sl * 8) * 2;
        bP1 = (const char*)B + ((size_t)(tn * 256 + r) * E_DIM + sl * 8) * 2;
    }

    // prologue: stage slots 0,1,2 (12 GLD)
#pragma unroll
    for (int t = 0; t < 3; ++t) {
        char* dA = ldsA + t * 16384 + wave * 1024;
        char* dB = ldsB + t * 16384 + wave * 1024;
        GLD(aP0, dA); GLD(aP1, dA + 8192);
        GLD(bP0, dB); GLD(bP1, dB + 8192);
        aP0 += 64; aP1 += 64; bP0 += 64; bP1 += 64;
    }
    asm volatile("s_waitcnt vmcnt(4)" ::: "memory");   // my slots 0,1 done
    __builtin_amdgcn_s_barrier();                      // global: slots 0,1 published
    SBAR();

    f32x4 acc[8][4] = {};
    bf16x8 aM0[4], aM1[4], bN0[2], bN1[2];

    // entry reads: slot 0
#pragma unroll
    for (int f = 0; f < 4; ++f)
        aM0[f] = *reinterpret_cast<const bf16x8*>(ldsA + (wm * 128 + f * 16 + fr) * 64 + sp * 16);
#pragma unroll
    for (int n = 0; n < 2; ++n)
        bN0[n] = *reinterpret_cast<const bf16x8*>(ldsB + (wn * 64 + n * 16 + fr) * 64 + sp * 16);
#pragma unroll
    for (int n = 0; n < 2; ++n)
        bN1[n] = *reinterpret_cast<const bf16x8*>(ldsB + (wn * 64 + 32 + n * 16 + fr) * 64 + sp * 16);
    SBAR();

    for (int kt = 0; kt < NKT - 3; ++kt)
        ktile<4, true, true>(ldsA, ldsB, kt, tid, wave, wm, wn, fr, sp,
                             aP0, aP1, bP0, bP1, aM0, aM1, bN0, bN1, acc);
    ktile<0, false, true >(ldsA, ldsB, NKT - 3, tid, wave, wm, wn, fr, sp,
                           aP0, aP1, bP0, bP1, aM0, aM1, bN0, bN1, acc);
    ktile<0, false, true >(ldsA, ldsB, NKT - 2, tid, wave, wm, wn, fr, sp,
                           aP0, aP1, bP0, bP1, aM0, aM1, bN0, bN1, acc);
    ktile<0, false, false>(ldsA, ldsB, NKT - 1, tid, wave, wm, wn, fr, sp,
                           aP0, aP1, bP0, bP1, aM0, aM1, bN0, bN1, acc);

    // ---- epilogue: per 64-row band, transpose through LDS, then stream out
    // full-line nontemporal f32x4 stores (R18-verified).
    float* bandbuf = (float*)lds;      // 64 KiB = 64 rows x 256 cols x 4B
    const int q4 = (lane >> 4) * 4;
#pragma unroll
    for (int b = 0; b < 4; ++b) {
        __syncthreads();               // K-loop reads / previous band stores done
        if (wm == (b >> 1)) {
            const int mi0 = (b & 1) * 4;
#pragma unroll
            for (int m = 0; m < 4; ++m)
#pragma unroll
                for (int ni = 0; ni < 4; ++ni)
#pragma unroll
                    for (int j = 0; j < 4; ++j)
                        bandbuf[(m * 16 + q4 + j) * 256 + wn * 64 + ni * 16 + fr] =
                            acc[mi0 + m][ni][j];
        }
        __syncthreads();
        const int rbase = tid >> 6;        // 0..7
        const int c4 = (tid & 63) * 4;     // col in floats
#pragma unroll
        for (int r8 = 0; r8 < 8; ++r8) {
            const int row = r8 * 8 + rbase;
            f32x4 v = *reinterpret_cast<const f32x4*>(&bandbuf[row * 256 + c4]);
            __builtin_nontemporal_store(v, reinterpret_cast<f32x4*>(
                &C[(size_t)(tm * 256 + b * 64 + row) * N_DIM + tn * 256 + c4]));
        }
    }
}

extern "C" void kernel_launch(void* const* d_in, const int* in_sizes, int n_in,
                              void* d_out, int out_size, void* d_ws, size_t ws_size,
                              hipStream_t stream) {
    const float* A = (const float*)d_in[0];   // DV2_H        [N, E]
    const float* B = (const float*)d_in[1];   // invDE_HT_DV2 [E, N]
    const float* W = (const float*)d_in[2];   // W            [E]
    float* C = (float*)d_out;                 // G            [N, N] fp32

    __hip_bfloat16* Abf  = (__hip_bfloat16*)d_ws;               // 32 MB
    __hip_bfloat16* Btbf = Abf + (size_t)N_DIM * E_DIM;         // 32 MB

    cvtA<<<(N_DIM * (size_t)E_DIM) / 8 / 256, 256, 0, stream>>>(A, Abf);
    dim3 tgrid(N_DIM / 32, E_DIM / 32);
    cvtB<<<tgrid, 256, 0, stream>>>(B, W, Btbf);
    gemm_bt<<<(N_DIM / 256) * (N_DIM / 256), 512, 0, stream>>>(Abf, Btbf, C);
}